// Round 24
// baseline (354.068 us; speedup 1.0000x reference)
//
#include <hip/hip_runtime.h>
#include <hip/hip_bf16.h>
#include <stdint.h>

// ---------------------------------------------------------------------------
// GPT-2 block on MI355X (gfx950). Round 24:
//  Round-23 state (334us) + GEMM MFMA shape 16x16x32 -> 32x32x16 (bt8):
//  17% fewer matrix-pipe cycles per FLOP (2382 vs 2075 TF ubench), half the
//  MFMA instruction count. Per-wave 64x64 = 2x2 32-tiles, acc f32x16[2][2]
//  (same 64 AGPR). C/D layout (col=lane&31, row=(r&3)+8(r>>2)+4(lane>>5))
//  reused from the attn kernel where it is verified. Everything else as r23.
// ---------------------------------------------------------------------------

typedef short bf16x8 __attribute__((ext_vector_type(8)));
typedef float f32x4  __attribute__((ext_vector_type(4)));
typedef float f32x16 __attribute__((ext_vector_type(16)));
typedef short s16x4  __attribute__((ext_vector_type(4)));

__device__ __forceinline__ short f2bf(float f) {
  union { float f; uint32_t u; } a;
  a.f = f;
  uint32_t r = a.u + 0x7fffu + ((a.u >> 16) & 1u);  // RNE
  return (short)(r >> 16);
}

__device__ __forceinline__ float bf2f(short s) {
  union { uint32_t u; float f; } x;
  x.u = ((uint32_t)(unsigned short)s) << 16;
  return x.f;
}

__device__ __forceinline__ unsigned cvt_pk_bf16(float lo, float hi_) {
  unsigned r;
  asm("v_cvt_pk_bf16_f32 %0, %1, %2" : "=v"(r) : "v"(lo), "v"(hi_));
  return r;
}

__device__ __forceinline__ float ex2(float x) {   // D = 2^x, raw HW op
  float r;
  asm("v_exp_f32 %0, %1" : "=v"(r) : "v"(x));
  return r;
}

__device__ __forceinline__ float rcp(float x) {
  float r;
  asm("v_rcp_f32 %0, %1" : "=v"(r) : "v"(x));
  return r;
}

__device__ __forceinline__ float m3(float a, float b, float c) {
  return fmaxf(fmaxf(a, b), c);   // clang fuses to v_max3_f32
}

__device__ __forceinline__ void gload_lds16(const void* g, void* l) {
  __builtin_amdgcn_global_load_lds(
      (const __attribute__((address_space(1))) void*)g,
      (__attribute__((address_space(3))) void*)l, 16, 0, 0);
}

__device__ __forceinline__ float gelu_f(float x) {
  float y = 0.7978845608028654f * (x + 0.044715f * x * x * x);
  y = fminf(fmaxf(y, -20.f), 20.f);
  float e = __expf(2.f * y);
  return 0.5f * x * (1.f + (e - 1.f) / (e + 1.f));  // tanh via exp
}

// ---------------- fused prologue: weight cvt + bias concat + LN1 ------------
struct ProArgs {
  const float* s[6];
  short* d[6];
  int off[7];                 // prefix offsets in float4 units (cvt ranges)
  int ncvt;                   // number of cvt blocks
  const float* bq; const float* bk; const float* bv; float* bqkv;
  const float* h; const float* g; const float* b; short* y;  // LN1
};

__global__ __launch_bounds__(256)
void prologue(ProArgs a) {
  const int bid = blockIdx.x;
  const int t = threadIdx.x;
  if (bid < a.ncvt) {
    const int i = bid * 256 + t;
#pragma unroll
    for (int k = 0; k < 6; ++k) {
      if (i >= a.off[k] && i < a.off[k + 1]) {
        const int j = i - a.off[k];
        float4 v = ((const float4*)a.s[k])[j];
        s16x4 o;
        o[0] = f2bf(v.x); o[1] = f2bf(v.y); o[2] = f2bf(v.z); o[3] = f2bf(v.w);
        ((s16x4*)a.d[k])[j] = o;
      }
    }
    return;
  }
  if (bid == a.ncvt) {
    ((float4*)a.bqkv)[t]       = ((const float4*)a.bq)[t];
    ((float4*)a.bqkv)[256 + t] = ((const float4*)a.bk)[t];
    ((float4*)a.bqkv)[512 + t] = ((const float4*)a.bv)[t];
    return;
  }
  const long row = bid - a.ncvt - 1;
  const float4 v = ((const float4*)(a.h + row * 1024))[t];
  float x0 = v.x, x1 = v.y, x2 = v.z, x3 = v.w;
  float s  = x0 + x1 + x2 + x3;
  float ss = x0 * x0 + x1 * x1 + x2 * x2 + x3 * x3;
#pragma unroll
  for (int m = 1; m < 64; m <<= 1) {
    s  += __shfl_xor(s, m);
    ss += __shfl_xor(ss, m);
  }
  __shared__ float rs[4], rss[4];
  const int wid = t >> 6, lane = t & 63;
  if (lane == 0) { rs[wid] = s; rss[wid] = ss; }
  __syncthreads();
  s  = rs[0] + rs[1] + rs[2] + rs[3];
  ss = rss[0] + rss[1] + rss[2] + rss[3];
  const float mu   = s * (1.f / 1024.f);
  const float var  = ss * (1.f / 1024.f) - mu * mu;
  const float rstd = rsqrtf(var + 1e-5f);
  const float4 gv = ((const float4*)a.g)[t];
  const float4 bv4 = ((const float4*)a.b)[t];
  s16x4 ov;
  ov[0] = f2bf((x0 - mu) * rstd * gv.x + bv4.x);
  ov[1] = f2bf((x1 - mu) * rstd * gv.y + bv4.y);
  ov[2] = f2bf((x2 - mu) * rstd * gv.z + bv4.z);
  ov[3] = f2bf((x3 - mu) * rstd * gv.w + bv4.w);
  *(s16x4*)(a.y + row * 1024 + t * 4) = ov;
}

// ------------------------------- LayerNorm (bf16 in) ------------------------
__global__ __launch_bounds__(256)
void ln_fwd_bf16(const short* __restrict__ xv_, const float* __restrict__ g,
                 const float* __restrict__ b, short* __restrict__ y) {
  const long row = blockIdx.x;
  const int t = threadIdx.x;
  const s16x4 v = ((const s16x4*)(xv_ + row * 1024))[t];
  float x0 = bf2f(v[0]), x1 = bf2f(v[1]), x2 = bf2f(v[2]), x3 = bf2f(v[3]);
  float s  = x0 + x1 + x2 + x3;
  float ss = x0 * x0 + x1 * x1 + x2 * x2 + x3 * x3;
#pragma unroll
  for (int m = 1; m < 64; m <<= 1) {
    s  += __shfl_xor(s, m);
    ss += __shfl_xor(ss, m);
  }
  __shared__ float rs[4], rss[4];
  const int wid = t >> 6, lane = t & 63;
  if (lane == 0) { rs[wid] = s; rss[wid] = ss; }
  __syncthreads();
  s  = rs[0] + rs[1] + rs[2] + rs[3];
  ss = rss[0] + rss[1] + rss[2] + rss[3];
  const float mu   = s * (1.f / 1024.f);
  const float var  = ss * (1.f / 1024.f) - mu * mu;
  const float rstd = rsqrtf(var + 1e-5f);
  const float4 gv = ((const float4*)g)[t];
  const float4 bv = ((const float4*)b)[t];
  s16x4 ov;
  ov[0] = f2bf((x0 - mu) * rstd * gv.x + bv.x);
  ov[1] = f2bf((x1 - mu) * rstd * gv.y + bv.y);
  ov[2] = f2bf((x2 - mu) * rstd * gv.z + bv.z);
  ov[3] = f2bf((x3 - mu) * rstd * gv.w + bv.w);
  *(s16x4*)(y + row * 1024 + t * 4) = ov;
}

// -------- GEMM 128x128 (NT, BK=128, single-buf, 64x64/wave, 32x32 MFMA) -----
// 32 MFMA(32x32x16) per barrier-pair; 16-slot granule XOR; L2 supertile
// remap; setprio around the MFMA cluster.
// C/D layout: col = lane&31, row = (r&3) + 8*(r>>2) + 4*(lane>>5).
template <int OUT_BF16, int HAS_RES, int HAS_GELU, int SCALE_Q, int V_TRANS,
          int RES_BF16>
__global__ __launch_bounds__(256, 2)
void gemm_bt8(const short* __restrict__ A, const short* __restrict__ W,
              const float* __restrict__ bias, const void* __restrict__ res,
              void* __restrict__ out, int M, int N, int K,
              short* __restrict__ vtg, int Sp, int Hp) {
  __shared__ short As[128 * 128];
  __shared__ short Bs[128 * 128];
  const int tid = threadIdx.x;
  const int wid = tid >> 6, lane = tid & 63;
  const int l31 = lane & 31, hi = lane >> 5;
  const int wm = wid >> 1, wn = wid & 1;

  const int nbx = N >> 7;
  const int nbr = M >> 7;
  const int nwg = nbx * nbr;
  int flat = (int)blockIdx.x;
  if ((nwg & 7) == 0) flat = (flat & 7) * (nwg >> 3) + (flat >> 3);
  int brow_b, bcol_b;
  if ((nbr & 7) == 0 && (nbx & 3) == 0) {
    const int nrg = nbr >> 3;
    const int g = flat >> 5, w = flat & 31;
    const int rg = g % nrg, cg = g / nrg;
    brow_b = rg * 8 + (w & 7);
    bcol_b = cg * 4 + (w >> 3);
  } else {
    brow_b = flat / nbx;
    bcol_b = flat % nbx;
  }
  const int brow = brow_b * 128, bcol = bcol_b * 128;

  f32x16 acc[2][2] = {};                      // [mt][nt]

  const int r0 = tid >> 4, g0 = tid & 15;     // staging: row-in-16chunk, slot

  // fragment rows (loop-invariant): A rows / W rows read by this lane
  int ar[2], br[2];
#pragma unroll
  for (int mt = 0; mt < 2; ++mt) ar[mt] = wm * 64 + mt * 32 + l31;
#pragma unroll
  for (int nt = 0; nt < 2; ++nt) br[nt] = wn * 64 + nt * 32 + l31;

  for (int kt = 0; kt < K; kt += 128) {
    __syncthreads();
#pragma unroll
    for (int i = 0; i < 8; ++i) {
      const int row = i * 16 + r0;
      gload_lds16(A + (long)(brow + row) * K + kt + 8 * (g0 ^ (row & 15)),
                  &As[(i * 256 + tid) * 8]);
      gload_lds16(W + (long)(bcol + row) * K + kt + 8 * (g0 ^ (row & 15)),
                  &Bs[(i * 256 + tid) * 8]);
    }
    __syncthreads();

    __builtin_amdgcn_s_setprio(1);
#pragma unroll
    for (int kk = 0; kk < 8; ++kk) {
      const int gc = 2 * kk + hi;             // 16B granule for this lane
      bf16x8 af[2], bf[2];
#pragma unroll
      for (int mt = 0; mt < 2; ++mt)
        af[mt] = *(const bf16x8*)&As[ar[mt] * 128 + 8 * (gc ^ (ar[mt] & 15))];
#pragma unroll
      for (int nt = 0; nt < 2; ++nt)
        bf[nt] = *(const bf16x8*)&Bs[br[nt] * 128 + 8 * (gc ^ (br[nt] & 15))];
#pragma unroll
      for (int mt = 0; mt < 2; ++mt)
#pragma unroll
        for (int nt = 0; nt < 2; ++nt)
          acc[mt][nt] = __builtin_amdgcn_mfma_f32_32x32x16_bf16(
              af[mt], bf[nt], acc[mt][nt], 0, 0, 0);
    }
    __builtin_amdgcn_s_setprio(0);
  }

  if (V_TRANS && bcol >= 2 * (N / 3)) {
    // V third: write transposed into vtg. token = brow + wm*64 + mt*32 +
    // (r&3) + 8*(r>>2) + 4*hi; tokens r&3 are consecutive -> s16x4 stores.
    const int bidx = brow / Sp;
    const int s0 = brow - bidx * Sp + wm * 64;
#pragma unroll
    for (int nt = 0; nt < 2; ++nt) {
      const int col = bcol + wn * 64 + nt * 32 + l31;
      const int c1 = col - 2 * (N / 3);
      const int hh = c1 >> 6, dh = c1 & 63;
      const float bb = bias[col];
      short* dst = vtg + ((long)(bidx * Hp + hh) * 64 + dh) * Sp + s0;
#pragma unroll
      for (int mt = 0; mt < 2; ++mt) {
#pragma unroll
        for (int rq = 0; rq < 4; ++rq) {
          s16x4 ov;
#pragma unroll
          for (int j = 0; j < 4; ++j)
            ov[j] = f2bf(acc[mt][nt][rq * 4 + j] + bb);
          *(s16x4*)(dst + mt * 32 + rq * 8 + hi * 4) = ov;
        }
      }
    }
    return;
  }

#pragma unroll
  for (int nt = 0; nt < 2; ++nt) {
    const int col = bcol + wn * 64 + nt * 32 + l31;
    const float bb = bias[col];
    const bool doScale = SCALE_Q && (col < N / 3);
#pragma unroll
    for (int mt = 0; mt < 2; ++mt) {
#pragma unroll
      for (int r = 0; r < 16; ++r) {
        const long row = brow + wm * 64 + mt * 32 + (r & 3) + 8 * (r >> 2) + 4 * hi;
        float vv = acc[mt][nt][r] + bb;
        if (HAS_GELU) vv = gelu_f(vv);
        if (HAS_RES) {
          if (RES_BF16) vv += bf2f(((const short*)res)[row * N + col]);
          else          vv += ((const float*)res)[row * N + col];
        }
        if (SCALE_Q && doScale) vv *= 0.18033688f;   // 1/8 * log2(e)
        if (OUT_BF16) ((short*)out)[row * N + col] = f2bf(vv);
        else          ((float*)out)[row * N + col] = vv;
      }
    }
  }
}

// --------------------------- causal flash attention -------------------------
__global__ __launch_bounds__(256, 4)
void attn_fwd2(const short* __restrict__ qg, const short* __restrict__ kg,
               const short* __restrict__ vtg, short* __restrict__ og,
               int S, int ldq, int D, int H) {
  const int tid = threadIdx.x, wid = tid >> 6, lane = tid & 63;
  const int l31 = lane & 31, hi = lane >> 5;
  const int fid = blockIdx.x;
  const int bh = fid & 63;
  const int b = bh / H, hh = bh % H;
  static const int perm[16] = {15, 0, 8, 7, 1, 14, 6, 9, 13, 2, 10, 5, 3, 12, 4, 11};
  const int qt = perm[(fid >> 6) & 15];
  const int q0 = qt * 128;
  const long qbase = (long)b * S * ldq + hh * 64;
  const long obase = (long)b * S * D + hh * 64;
  const long vbase = (long)bh * 64 * S;

  __shared__ short Ks[2][64 * 64];
  __shared__ short Vs[2][64 * 64];

  auto STAGE = [&](int buf, int k0) {
#pragma unroll
    for (int i = 0; i < 2; ++i) {
      const int c = i * 256 + tid;
      const int row = c >> 3, gl = c & 7;
      gload_lds16(&kg[qbase + (long)(k0 + row) * ldq + 8 * (gl ^ (row & 7))],
                  &Ks[buf][(i * 256 + wid * 64) * 8]);
      gload_lds16(&vtg[vbase + (long)row * S + k0 + 8 * (gl ^ (row & 7))],
                  &Vs[buf][(i * 256 + wid * 64) * 8]);
    }
  };

  const int qw = q0 + wid * 32;
  const int qv = qw + l31;

  bf16x8 qf[4];
#pragma unroll
  for (int s = 0; s < 4; ++s)
    qf[s] = *(const bf16x8*)&qg[qbase + (long)qv * ldq + 16 * s + 8 * hi];

  f32x16 oa[2] = {};
  float mr = -3000.f, lr = 0.f;

  const int ntiles = qt * 2 + 2;

  STAGE(0, 0);
  for (int t = 0; t < ntiles; ++t) {
    const int cur = t & 1;
    const int k0 = t * 64;
    if (t + 1 < ntiles) {
      STAGE(cur ^ 1, k0 + 64);
      asm volatile("s_waitcnt vmcnt(4)" ::: "memory");
    } else {
      asm volatile("s_waitcnt vmcnt(0)" ::: "memory");
    }
    __builtin_amdgcn_s_barrier();

    if (k0 < qw + 32) {
      f32x16 st[2] = {};
      __builtin_amdgcn_s_setprio(1);
#pragma unroll
      for (int s = 0; s < 4; ++s) {
        const int g = ((s << 1) | hi) ^ (l31 & 7);
        bf16x8 kf0 = *(const bf16x8*)&Ks[cur][l31 * 64 + 8 * g];
        bf16x8 kf1 = *(const bf16x8*)&Ks[cur][(32 + l31) * 64 + 8 * g];
        st[0] = __builtin_amdgcn_mfma_f32_32x32x16_bf16(kf0, qf[s], st[0], 0, 0, 0);
        st[1] = __builtin_amdgcn_mfma_f32_32x32x16_bf16(kf1, qf[s], st[1], 0, 0, 0);
      }
      __builtin_amdgcn_s_setprio(0);

      const bool need_mask = (k0 + 63 > qw);
      float pv[2][16];
#pragma unroll
      for (int kb = 0; kb < 2; ++kb)
#pragma unroll
        for (int r = 0; r < 16; ++r) {
          float v = st[kb][r];           // Q pre-scaled: log2 domain
          if (need_mask) {
            const int key = k0 + kb * 32 + (r & 3) + 8 * (r >> 2) + 4 * hi;
            if (key > qv) v = -1e30f;
          }
          pv[kb][r] = v;
        }

      float rm = fmaxf(pv[0][0], pv[0][1]);
#pragma unroll
      for (int r = 2; r < 16; r += 2) rm = m3(rm, pv[0][r], pv[0][r + 1]);
#pragma unroll
      for (int r = 0; r < 16; r += 2) rm = m3(rm, pv[1][r], pv[1][r + 1]);
      rm = fmaxf(rm, __shfl_xor(rm, 32));

      const bool defer = (bool)__all(rm <= mr + 8.f);
      const float mn = defer ? mr : fmaxf(mr, rm);

      float a0 = 0.f, a1 = 0.f, a2 = 0.f, a3 = 0.f;
#pragma unroll
      for (int r = 0; r < 8; ++r) {
        float p0 = ex2(pv[0][r] - mn);      pv[0][r] = p0;      a0 += p0;
        float p1 = ex2(pv[0][8 + r] - mn);  pv[0][8 + r] = p1;  a1 += p1;
        float p2 = ex2(pv[1][r] - mn);      pv[1][r] = p2;      a2 += p2;
        float p3 = ex2(pv[1][8 + r] - mn);  pv[1][8 + r] = p3;  a3 += p3;
      }
      float ls = (a0 + a1) + (a2 + a3);
      ls += __shfl_xor(ls, 32);

      if (!defer) {
        const float alpha = ex2(mr - mn);
        lr = lr * alpha + ls;
        mr = mn;
#pragma unroll
        for (int r = 0; r < 16; ++r) {
          const int crow = (r & 3) + 8 * (r >> 2) + 4 * hi;
          const float ar = __shfl(alpha, crow | (lane & 32));
          oa[0][r] *= ar;
          oa[1][r] *= ar;
        }
      } else {
        lr += ls;
      }

      bf16x8 pa[4];
#pragma unroll
      for (int kb = 0; kb < 2; ++kb) {
        unsigned pk[8], ex[8];
#pragma unroll
        for (int i2 = 0; i2 < 8; ++i2)
          pk[i2] = cvt_pk_bf16(pv[kb][2 * i2], pv[kb][2 * i2 + 1]);
#pragma unroll
        for (int i2 = 0; i2 < 8; ++i2)
          ex[i2] = (unsigned)__shfl_xor((int)pk[i2], 32);
        union { unsigned u[4]; bf16x8 v8; } f0, f1;
        f0.u[0] = hi ? ex[2] : pk[0];
        f0.u[1] = hi ? ex[3] : pk[1];
        f0.u[2] = hi ? pk[2] : ex[0];
        f0.u[3] = hi ? pk[3] : ex[1];
        f1.u[0] = hi ? ex[6] : pk[4];
        f1.u[1] = hi ? ex[7] : pk[5];
        f1.u[2] = hi ? pk[6] : ex[4];
        f1.u[3] = hi ? pk[7] : ex[5];
        pa[2 * kb]     = f0.v8;
        pa[2 * kb + 1] = f1.v8;
      }

      __builtin_amdgcn_s_setprio(1);
#pragma unroll
      for (int s = 0; s < 4; ++s) {
        const int g = ((s << 1) | hi) ^ (l31 & 7);
        bf16x8 vf0 = *(const bf16x8*)&Vs[cur][l31 * 64 + 8 * g];
        bf16x8 vf1 = *(const bf16x8*)&Vs[cur][(32 + l31) * 64 + 8 * g];
        oa[0] = __builtin_amdgcn_mfma_f32_32x32x16_bf16(pa[s], vf0, oa[0], 0, 0, 0);
        oa[1] = __builtin_amdgcn_mfma_f32_32x32x16_bf16(pa[s], vf1, oa[1], 0, 0, 0);
      }
      __builtin_amdgcn_s_setprio(0);
    }

    asm volatile("s_waitcnt lgkmcnt(0)" ::: "memory");
    __builtin_amdgcn_s_barrier();
  }

  const float linv = rcp(lr);
#pragma unroll
  for (int r = 0; r < 16; ++r) {
    const int crow = (r & 3) + 8 * (r >> 2) + 4 * hi;
    const float li = __shfl(linv, crow | (lane & 32));
    const long row = qw + crow;
    og[obase + row * D + l31]      = f2bf(oa[0][r] * li);
    og[obase + row * D + 32 + l31] = f2bf(oa[1][r] * li);
  }
}

// ------------------------------- launcher -----------------------------------
extern "C" void kernel_launch(void* const* d_in, const int* in_sizes, int n_in,
                              void* d_out, int out_size, void* d_ws, size_t ws_size,
                              hipStream_t stream) {
  (void)in_sizes; (void)n_in; (void)out_size; (void)ws_size;
  const float* h     = (const float*)d_in[0];
  const float* ln1_g = (const float*)d_in[1];
  const float* ln1_b = (const float*)d_in[2];
  const float* wq    = (const float*)d_in[3];
  const float* bq    = (const float*)d_in[4];
  const float* wk    = (const float*)d_in[5];
  const float* bk    = (const float*)d_in[6];
  const float* wv    = (const float*)d_in[7];
  const float* bv    = (const float*)d_in[8];
  const float* wo    = (const float*)d_in[9];
  const float* bo    = (const float*)d_in[10];
  const float* ln2_g = (const float*)d_in[11];
  const float* ln2_b = (const float*)d_in[12];
  const float* wfc   = (const float*)d_in[13];
  const float* bfc   = (const float*)d_in[14];
  const float* wproj = (const float*)d_in[15];
  const float* bproj = (const float*)d_in[16];

  const int B = 4, S = 2048, D = 1024, H = 16, F = 4096, T = B * S;
  const int D3 = 3 * D;

  char* ws = (char*)d_ws;
  size_t off = 0;
  auto alloc = [&](size_t bytes) {
    void* p = ws + off;
    off += (bytes + 255) & ~(size_t)255;
    return p;
  };
  short* xb   = (short*)alloc((size_t)T * D * 2);     // ln1(x) / ln2(x)
  short* qkv  = (short*)alloc((size_t)T * D3 * 2);    // fused QKV out [T,3D]
  short* ob   = (short*)alloc((size_t)T * D * 2);     // attn out
  short* h2b  = (short*)alloc((size_t)T * D * 2);     // post-attn residual (bf16)
  short* vtg  = (short*)alloc((size_t)T * D * 2);     // V^T [B*H*64, S]
  short* wqkvb  = (short*)alloc((size_t)D3 * D * 2);
  short* wob    = (short*)alloc((size_t)D * D * 2);
  short* wfcb   = (short*)alloc((size_t)F * D * 2);
  short* wprojb = (short*)alloc((size_t)D * F * 2);
  float* bqkv   = (float*)alloc((size_t)D3 * 4);
  short* ub  = qkv;           // u [T,F] aliases qkv(48MB)+ob(16MB), dead by FC

  ProArgs pa;
  const int nqq = D * D / 4;
  pa.s[0] = wq;    pa.d[0] = wqkvb;
  pa.s[1] = wk;    pa.d[1] = wqkvb + (size_t)D * D;
  pa.s[2] = wv;    pa.d[2] = wqkvb + (size_t)2 * D * D;
  pa.s[3] = wo;    pa.d[3] = wob;
  pa.s[4] = wfc;   pa.d[4] = wfcb;
  pa.s[5] = wproj; pa.d[5] = wprojb;
  pa.off[0] = 0;
  pa.off[1] = nqq;
  pa.off[2] = 2 * nqq;
  pa.off[3] = 3 * nqq;
  pa.off[4] = 4 * nqq;
  pa.off[5] = 4 * nqq + F * D / 4;
  pa.off[6] = 4 * nqq + 2 * (F * D / 4);
  pa.ncvt = pa.off[6] / 256;
  pa.bq = bq; pa.bk = bk; pa.bv = bv; pa.bqkv = bqkv;
  pa.h = h; pa.g = ln1_g; pa.b = ln1_b; pa.y = xb;
  prologue<<<dim3(pa.ncvt + 1 + T), 256, 0, stream>>>(pa);

  // attention sub-block (V transposed by QKV epilogue)
  gemm_bt8<1, 0, 0, 1, 1, 0><<<dim3((T / 128) * (D3 / 128)), 256, 0, stream>>>(
      xb, wqkvb, bqkv, nullptr, qkv, T, D3, D, vtg, S, H);
  attn_fwd2<<<dim3((S / 128) * (B * H / 64) * 64), 256, 0, stream>>>(
      qkv, qkv + D, vtg, ob, S, D3, D, H);
  // Wo: out bf16 h2b = acc + bo + h (fp32 res)
  gemm_bt8<1, 1, 0, 0, 0, 0><<<dim3((T / 128) * (D / 128)), 256, 0, stream>>>(
      ob, wob, bo, h, h2b, T, D, D, nullptr, 0, 0);

  // MLP sub-block
  ln_fwd_bf16<<<dim3(T), 256, 0, stream>>>(h2b, ln2_g, ln2_b, xb);
  gemm_bt8<1, 0, 1, 0, 0, 0><<<dim3((T / 128) * (F / 128)), 256, 0, stream>>>(
      xb, wfcb, bfc, nullptr, ub, T, F, D, nullptr, 0, 0);
  // Proj: out fp32 d_out = acc + bproj + h2b (bf16 res)
  gemm_bt8<0, 1, 0, 0, 0, 1><<<dim3((T / 128) * (D / 128)), 256, 0, stream>>>(
      ub, wprojb, bproj, h2b, (float*)d_out, T, D, F, nullptr, 0, 0);
}

// Round 25
// 333.205 us; speedup vs baseline: 1.0626x; 1.0626x over previous
//
#include <hip/hip_runtime.h>
#include <hip/hip_bf16.h>
#include <stdint.h>

// ---------------------------------------------------------------------------
// GPT-2 block on MI355X (gfx950). Round 25 = round 23 restored (334us best).
// Round-24's 32x32x16 MFMA shape regressed (8-deep serial acc chains of
// 8-cyc MFMAs with only 4 accumulators < needed ILP); reverted to 16x16x32.
// Stack: fused prologue (cvt+bias+LN1), bt7 GEMM (BK=128, 64 MFMA/barrier,
// XOR-16 swizzle, L2 supertile remap, setprio), fused QKV (+Q-scale,
// +V-transpose epilogue), swapped-QK^T in-reg-softmax attention (ex2/rcp,
// defer-max, balanced qt permutation), bf16 h2 residual.
// ---------------------------------------------------------------------------

typedef short bf16x8 __attribute__((ext_vector_type(8)));
typedef float f32x4  __attribute__((ext_vector_type(4)));
typedef float f32x16 __attribute__((ext_vector_type(16)));
typedef short s16x4  __attribute__((ext_vector_type(4)));

__device__ __forceinline__ short f2bf(float f) {
  union { float f; uint32_t u; } a;
  a.f = f;
  uint32_t r = a.u + 0x7fffu + ((a.u >> 16) & 1u);  // RNE
  return (short)(r >> 16);
}

__device__ __forceinline__ float bf2f(short s) {
  union { uint32_t u; float f; } x;
  x.u = ((uint32_t)(unsigned short)s) << 16;
  return x.f;
}

__device__ __forceinline__ unsigned cvt_pk_bf16(float lo, float hi_) {
  unsigned r;
  asm("v_cvt_pk_bf16_f32 %0, %1, %2" : "=v"(r) : "v"(lo), "v"(hi_));
  return r;
}

__device__ __forceinline__ float ex2(float x) {   // D = 2^x, raw HW op
  float r;
  asm("v_exp_f32 %0, %1" : "=v"(r) : "v"(x));
  return r;
}

__device__ __forceinline__ float rcp(float x) {
  float r;
  asm("v_rcp_f32 %0, %1" : "=v"(r) : "v"(x));
  return r;
}

__device__ __forceinline__ float m3(float a, float b, float c) {
  return fmaxf(fmaxf(a, b), c);   // clang fuses to v_max3_f32
}

__device__ __forceinline__ void gload_lds16(const void* g, void* l) {
  __builtin_amdgcn_global_load_lds(
      (const __attribute__((address_space(1))) void*)g,
      (__attribute__((address_space(3))) void*)l, 16, 0, 0);
}

__device__ __forceinline__ float gelu_f(float x) {
  float y = 0.7978845608028654f * (x + 0.044715f * x * x * x);
  y = fminf(fmaxf(y, -20.f), 20.f);
  float e = __expf(2.f * y);
  return 0.5f * x * (1.f + (e - 1.f) / (e + 1.f));  // tanh via exp
}

// ---------------- fused prologue: weight cvt + bias concat + LN1 ------------
struct ProArgs {
  const float* s[6];
  short* d[6];
  int off[7];                 // prefix offsets in float4 units (cvt ranges)
  int ncvt;                   // number of cvt blocks
  const float* bq; const float* bk; const float* bv; float* bqkv;
  const float* h; const float* g; const float* b; short* y;  // LN1
};

__global__ __launch_bounds__(256)
void prologue(ProArgs a) {
  const int bid = blockIdx.x;
  const int t = threadIdx.x;
  if (bid < a.ncvt) {
    const int i = bid * 256 + t;
#pragma unroll
    for (int k = 0; k < 6; ++k) {
      if (i >= a.off[k] && i < a.off[k + 1]) {
        const int j = i - a.off[k];
        float4 v = ((const float4*)a.s[k])[j];
        s16x4 o;
        o[0] = f2bf(v.x); o[1] = f2bf(v.y); o[2] = f2bf(v.z); o[3] = f2bf(v.w);
        ((s16x4*)a.d[k])[j] = o;
      }
    }
    return;
  }
  if (bid == a.ncvt) {
    // bias concat: 3 x 256 float4s
    ((float4*)a.bqkv)[t]       = ((const float4*)a.bq)[t];
    ((float4*)a.bqkv)[256 + t] = ((const float4*)a.bk)[t];
    ((float4*)a.bqkv)[512 + t] = ((const float4*)a.bv)[t];
    return;
  }
  // LN1 (fp32 input)
  const long row = bid - a.ncvt - 1;
  const float4 v = ((const float4*)(a.h + row * 1024))[t];
  float x0 = v.x, x1 = v.y, x2 = v.z, x3 = v.w;
  float s  = x0 + x1 + x2 + x3;
  float ss = x0 * x0 + x1 * x1 + x2 * x2 + x3 * x3;
#pragma unroll
  for (int m = 1; m < 64; m <<= 1) {
    s  += __shfl_xor(s, m);
    ss += __shfl_xor(ss, m);
  }
  __shared__ float rs[4], rss[4];
  const int wid = t >> 6, lane = t & 63;
  if (lane == 0) { rs[wid] = s; rss[wid] = ss; }
  __syncthreads();
  s  = rs[0] + rs[1] + rs[2] + rs[3];
  ss = rss[0] + rss[1] + rss[2] + rss[3];
  const float mu   = s * (1.f / 1024.f);
  const float var  = ss * (1.f / 1024.f) - mu * mu;
  const float rstd = rsqrtf(var + 1e-5f);
  const float4 gv = ((const float4*)a.g)[t];
  const float4 bv4 = ((const float4*)a.b)[t];
  s16x4 ov;
  ov[0] = f2bf((x0 - mu) * rstd * gv.x + bv4.x);
  ov[1] = f2bf((x1 - mu) * rstd * gv.y + bv4.y);
  ov[2] = f2bf((x2 - mu) * rstd * gv.z + bv4.z);
  ov[3] = f2bf((x3 - mu) * rstd * gv.w + bv4.w);
  *(s16x4*)(a.y + row * 1024 + t * 4) = ov;
}

// ------------------------------- LayerNorm (bf16 in) ------------------------
__global__ __launch_bounds__(256)
void ln_fwd_bf16(const short* __restrict__ xv_, const float* __restrict__ g,
                 const float* __restrict__ b, short* __restrict__ y) {
  const long row = blockIdx.x;
  const int t = threadIdx.x;
  const s16x4 v = ((const s16x4*)(xv_ + row * 1024))[t];
  float x0 = bf2f(v[0]), x1 = bf2f(v[1]), x2 = bf2f(v[2]), x3 = bf2f(v[3]);
  float s  = x0 + x1 + x2 + x3;
  float ss = x0 * x0 + x1 * x1 + x2 * x2 + x3 * x3;
#pragma unroll
  for (int m = 1; m < 64; m <<= 1) {
    s  += __shfl_xor(s, m);
    ss += __shfl_xor(ss, m);
  }
  __shared__ float rs[4], rss[4];
  const int wid = t >> 6, lane = t & 63;
  if (lane == 0) { rs[wid] = s; rss[wid] = ss; }
  __syncthreads();
  s  = rs[0] + rs[1] + rs[2] + rs[3];
  ss = rss[0] + rss[1] + rss[2] + rss[3];
  const float mu   = s * (1.f / 1024.f);
  const float var  = ss * (1.f / 1024.f) - mu * mu;
  const float rstd = rsqrtf(var + 1e-5f);
  const float4 gv = ((const float4*)g)[t];
  const float4 bv = ((const float4*)b)[t];
  s16x4 ov;
  ov[0] = f2bf((x0 - mu) * rstd * gv.x + bv.x);
  ov[1] = f2bf((x1 - mu) * rstd * gv.y + bv.y);
  ov[2] = f2bf((x2 - mu) * rstd * gv.z + bv.z);
  ov[3] = f2bf((x3 - mu) * rstd * gv.w + bv.w);
  *(s16x4*)(y + row * 1024 + t * 4) = ov;
}

// -------------- GEMM 128x128 (NT, BK=128, single-buf, 64x64/wave) -----------
// 64 MFMA per barrier-pair; 16-slot granule XOR; L2 supertile block remap;
// setprio around the MFMA cluster.
template <int OUT_BF16, int HAS_RES, int HAS_GELU, int SCALE_Q, int V_TRANS,
          int RES_BF16>
__global__ __launch_bounds__(256, 2)
void gemm_bt7(const short* __restrict__ A, const short* __restrict__ W,
              const float* __restrict__ bias, const void* __restrict__ res,
              void* __restrict__ out, int M, int N, int K,
              short* __restrict__ vtg, int Sp, int Hp) {
  __shared__ short As[128 * 128];
  __shared__ short Bs[128 * 128];
  const int tid = threadIdx.x;
  const int wid = tid >> 6, lane = tid & 63;
  const int l16 = lane & 15, lg = lane >> 4;
  const int wm = wid >> 1, wn = wid & 1;

  const int nbx = N >> 7;
  const int nbr = M >> 7;
  const int nwg = nbx * nbr;
  int flat = (int)blockIdx.x;
  if ((nwg & 7) == 0) flat = (flat & 7) * (nwg >> 3) + (flat >> 3);
  int brow_b, bcol_b;
  if ((nbr & 7) == 0 && (nbx & 3) == 0) {
    const int nrg = nbr >> 3;
    const int g = flat >> 5, w = flat & 31;
    const int rg = g % nrg, cg = g / nrg;
    brow_b = rg * 8 + (w & 7);
    bcol_b = cg * 4 + (w >> 3);
  } else {
    brow_b = flat / nbx;
    bcol_b = flat % nbx;
  }
  const int brow = brow_b * 128, bcol = bcol_b * 128;

  f32x4 acc[4][4] = {};

  const int r0 = tid >> 4, g0 = tid & 15;   // staging: row-in-16chunk, slot

  int ra[4], rb[4];
#pragma unroll
  for (int m = 0; m < 4; ++m) ra[m] = wm * 64 + m * 16 + l16;
#pragma unroll
  for (int n = 0; n < 4; ++n) rb[n] = wn * 64 + n * 16 + l16;

  for (int kt = 0; kt < K; kt += 128) {
    __syncthreads();
#pragma unroll
    for (int i = 0; i < 8; ++i) {
      const int row = i * 16 + r0;
      gload_lds16(A + (long)(brow + row) * K + kt + 8 * (g0 ^ (row & 15)),
                  &As[(i * 256 + tid) * 8]);
      gload_lds16(W + (long)(bcol + row) * K + kt + 8 * (g0 ^ (row & 15)),
                  &Bs[(i * 256 + tid) * 8]);
    }
    __syncthreads();

    __builtin_amdgcn_s_setprio(1);
#pragma unroll
    for (int kk = 0; kk < 4; ++kk) {
      bf16x8 af[4], bf[4];
#pragma unroll
      for (int m = 0; m < 4; ++m)
        af[m] = *(const bf16x8*)&As[ra[m] * 128 + 8 * ((kk * 4 + lg) ^ (ra[m] & 15))];
#pragma unroll
      for (int n = 0; n < 4; ++n)
        bf[n] = *(const bf16x8*)&Bs[rb[n] * 128 + 8 * ((kk * 4 + lg) ^ (rb[n] & 15))];
#pragma unroll
      for (int m = 0; m < 4; ++m)
#pragma unroll
        for (int n = 0; n < 4; ++n)
          acc[m][n] = __builtin_amdgcn_mfma_f32_16x16x32_bf16(af[m], bf[n], acc[m][n], 0, 0, 0);
    }
    __builtin_amdgcn_s_setprio(0);
  }

  if (V_TRANS && bcol >= 2 * (N / 3)) {
    const int bidx = brow / Sp;
    const int s0 = brow - bidx * Sp + wm * 64;
#pragma unroll
    for (int n = 0; n < 4; ++n) {
      const int col = bcol + wn * 64 + n * 16 + l16;
      const int c1 = col - 2 * (N / 3);
      const int hh = c1 >> 6, dh = c1 & 63;
      const float bb = bias[col];
      short* dst = vtg + ((long)(bidx * Hp + hh) * 64 + dh) * Sp + s0;
#pragma unroll
      for (int m = 0; m < 4; ++m) {
        s16x4 ov;
#pragma unroll
        for (int j = 0; j < 4; ++j) ov[j] = f2bf(acc[m][n][j] + bb);
        *(s16x4*)(dst + m * 16 + lg * 4) = ov;
      }
    }
    return;
  }

#pragma unroll
  for (int n = 0; n < 4; ++n) {
    const int col = bcol + wn * 64 + n * 16 + l16;
    const float bb = bias[col];
    const bool doScale = SCALE_Q && (col < N / 3);
#pragma unroll
    for (int m = 0; m < 4; ++m) {
#pragma unroll
      for (int j = 0; j < 4; ++j) {
        const long row = brow + wm * 64 + m * 16 + lg * 4 + j;
        float vv = acc[m][n][j] + bb;
        if (HAS_GELU) vv = gelu_f(vv);
        if (HAS_RES) {
          if (RES_BF16) vv += bf2f(((const short*)res)[row * N + col]);
          else          vv += ((const float*)res)[row * N + col];
        }
        if (SCALE_Q && doScale) vv *= 0.18033688f;   // 1/8 * log2(e)
        if (OUT_BF16) ((short*)out)[row * N + col] = f2bf(vv);
        else          ((float*)out)[row * N + col] = vv;
      }
    }
  }
}

// --------------------------- causal flash attention -------------------------
__global__ __launch_bounds__(256, 4)
void attn_fwd2(const short* __restrict__ qg, const short* __restrict__ kg,
               const short* __restrict__ vtg, short* __restrict__ og,
               int S, int ldq, int D, int H) {
  const int tid = threadIdx.x, wid = tid >> 6, lane = tid & 63;
  const int l31 = lane & 31, hi = lane >> 5;
  const int fid = blockIdx.x;
  const int bh = fid & 63;
  const int b = bh / H, hh = bh % H;
  static const int perm[16] = {15, 0, 8, 7, 1, 14, 6, 9, 13, 2, 10, 5, 3, 12, 4, 11};
  const int qt = perm[(fid >> 6) & 15];
  const int q0 = qt * 128;
  const long qbase = (long)b * S * ldq + hh * 64;
  const long obase = (long)b * S * D + hh * 64;
  const long vbase = (long)bh * 64 * S;

  __shared__ short Ks[2][64 * 64];
  __shared__ short Vs[2][64 * 64];

  auto STAGE = [&](int buf, int k0) {
#pragma unroll
    for (int i = 0; i < 2; ++i) {
      const int c = i * 256 + tid;
      const int row = c >> 3, gl = c & 7;
      gload_lds16(&kg[qbase + (long)(k0 + row) * ldq + 8 * (gl ^ (row & 7))],
                  &Ks[buf][(i * 256 + wid * 64) * 8]);
      gload_lds16(&vtg[vbase + (long)row * S + k0 + 8 * (gl ^ (row & 7))],
                  &Vs[buf][(i * 256 + wid * 64) * 8]);
    }
  };

  const int qw = q0 + wid * 32;
  const int qv = qw + l31;

  bf16x8 qf[4];
#pragma unroll
  for (int s = 0; s < 4; ++s)
    qf[s] = *(const bf16x8*)&qg[qbase + (long)qv * ldq + 16 * s + 8 * hi];

  f32x16 oa[2] = {};
  float mr = -3000.f, lr = 0.f;

  const int ntiles = qt * 2 + 2;

  STAGE(0, 0);
  for (int t = 0; t < ntiles; ++t) {
    const int cur = t & 1;
    const int k0 = t * 64;
    if (t + 1 < ntiles) {
      STAGE(cur ^ 1, k0 + 64);
      asm volatile("s_waitcnt vmcnt(4)" ::: "memory");
    } else {
      asm volatile("s_waitcnt vmcnt(0)" ::: "memory");
    }
    __builtin_amdgcn_s_barrier();

    if (k0 < qw + 32) {
      f32x16 st[2] = {};
      __builtin_amdgcn_s_setprio(1);
#pragma unroll
      for (int s = 0; s < 4; ++s) {
        const int g = ((s << 1) | hi) ^ (l31 & 7);
        bf16x8 kf0 = *(const bf16x8*)&Ks[cur][l31 * 64 + 8 * g];
        bf16x8 kf1 = *(const bf16x8*)&Ks[cur][(32 + l31) * 64 + 8 * g];
        st[0] = __builtin_amdgcn_mfma_f32_32x32x16_bf16(kf0, qf[s], st[0], 0, 0, 0);
        st[1] = __builtin_amdgcn_mfma_f32_32x32x16_bf16(kf1, qf[s], st[1], 0, 0, 0);
      }
      __builtin_amdgcn_s_setprio(0);

      const bool need_mask = (k0 + 63 > qw);
      float pv[2][16];
#pragma unroll
      for (int kb = 0; kb < 2; ++kb)
#pragma unroll
        for (int r = 0; r < 16; ++r) {
          float v = st[kb][r];           // Q pre-scaled: log2 domain
          if (need_mask) {
            const int key = k0 + kb * 32 + (r & 3) + 8 * (r >> 2) + 4 * hi;
            if (key > qv) v = -1e30f;
          }
          pv[kb][r] = v;
        }

      float rm = fmaxf(pv[0][0], pv[0][1]);
#pragma unroll
      for (int r = 2; r < 16; r += 2) rm = m3(rm, pv[0][r], pv[0][r + 1]);
#pragma unroll
      for (int r = 0; r < 16; r += 2) rm = m3(rm, pv[1][r], pv[1][r + 1]);
      rm = fmaxf(rm, __shfl_xor(rm, 32));

      const bool defer = (bool)__all(rm <= mr + 8.f);
      const float mn = defer ? mr : fmaxf(mr, rm);

      float a0 = 0.f, a1 = 0.f, a2 = 0.f, a3 = 0.f;
#pragma unroll
      for (int r = 0; r < 8; ++r) {
        float p0 = ex2(pv[0][r] - mn);      pv[0][r] = p0;      a0 += p0;
        float p1 = ex2(pv[0][8 + r] - mn);  pv[0][8 + r] = p1;  a1 += p1;
        float p2 = ex2(pv[1][r] - mn);      pv[1][r] = p2;      a2 += p2;
        float p3 = ex2(pv[1][8 + r] - mn);  pv[1][8 + r] = p3;  a3 += p3;
      }
      float ls = (a0 + a1) + (a2 + a3);
      ls += __shfl_xor(ls, 32);

      if (!defer) {
        const float alpha = ex2(mr - mn);
        lr = lr * alpha + ls;
        mr = mn;
#pragma unroll
        for (int r = 0; r < 16; ++r) {
          const int crow = (r & 3) + 8 * (r >> 2) + 4 * hi;
          const float ar = __shfl(alpha, crow | (lane & 32));
          oa[0][r] *= ar;
          oa[1][r] *= ar;
        }
      } else {
        lr += ls;
      }

      bf16x8 pa[4];
#pragma unroll
      for (int kb = 0; kb < 2; ++kb) {
        unsigned pk[8], ex[8];
#pragma unroll
        for (int i2 = 0; i2 < 8; ++i2)
          pk[i2] = cvt_pk_bf16(pv[kb][2 * i2], pv[kb][2 * i2 + 1]);
#pragma unroll
        for (int i2 = 0; i2 < 8; ++i2)
          ex[i2] = (unsigned)__shfl_xor((int)pk[i2], 32);
        union { unsigned u[4]; bf16x8 v8; } f0, f1;
        f0.u[0] = hi ? ex[2] : pk[0];
        f0.u[1] = hi ? ex[3] : pk[1];
        f0.u[2] = hi ? pk[2] : ex[0];
        f0.u[3] = hi ? pk[3] : ex[1];
        f1.u[0] = hi ? ex[6] : pk[4];
        f1.u[1] = hi ? ex[7] : pk[5];
        f1.u[2] = hi ? pk[6] : ex[4];
        f1.u[3] = hi ? pk[7] : ex[5];
        pa[2 * kb]     = f0.v8;
        pa[2 * kb + 1] = f1.v8;
      }

      __builtin_amdgcn_s_setprio(1);
#pragma unroll
      for (int s = 0; s < 4; ++s) {
        const int g = ((s << 1) | hi) ^ (l31 & 7);
        bf16x8 vf0 = *(const bf16x8*)&Vs[cur][l31 * 64 + 8 * g];
        bf16x8 vf1 = *(const bf16x8*)&Vs[cur][(32 + l31) * 64 + 8 * g];
        oa[0] = __builtin_amdgcn_mfma_f32_32x32x16_bf16(pa[s], vf0, oa[0], 0, 0, 0);
        oa[1] = __builtin_amdgcn_mfma_f32_32x32x16_bf16(pa[s], vf1, oa[1], 0, 0, 0);
      }
      __builtin_amdgcn_s_setprio(0);
    }

    asm volatile("s_waitcnt lgkmcnt(0)" ::: "memory");
    __builtin_amdgcn_s_barrier();
  }

  const float linv = rcp(lr);
#pragma unroll
  for (int r = 0; r < 16; ++r) {
    const int crow = (r & 3) + 8 * (r >> 2) + 4 * hi;
    const float li = __shfl(linv, crow | (lane & 32));
    const long row = qw + crow;
    og[obase + row * D + l31]      = f2bf(oa[0][r] * li);
    og[obase + row * D + 32 + l31] = f2bf(oa[1][r] * li);
  }
}

// ------------------------------- launcher -----------------------------------
extern "C" void kernel_launch(void* const* d_in, const int* in_sizes, int n_in,
                              void* d_out, int out_size, void* d_ws, size_t ws_size,
                              hipStream_t stream) {
  (void)in_sizes; (void)n_in; (void)out_size; (void)ws_size;
  const float* h     = (const float*)d_in[0];
  const float* ln1_g = (const float*)d_in[1];
  const float* ln1_b = (const float*)d_in[2];
  const float* wq    = (const float*)d_in[3];
  const float* bq    = (const float*)d_in[4];
  const float* wk    = (const float*)d_in[5];
  const float* bk    = (const float*)d_in[6];
  const float* wv    = (const float*)d_in[7];
  const float* bv    = (const float*)d_in[8];
  const float* wo    = (const float*)d_in[9];
  const float* bo    = (const float*)d_in[10];
  const float* ln2_g = (const float*)d_in[11];
  const float* ln2_b = (const float*)d_in[12];
  const float* wfc   = (const float*)d_in[13];
  const float* bfc   = (const float*)d_in[14];
  const float* wproj = (const float*)d_in[15];
  const float* bproj = (const float*)d_in[16];

  const int B = 4, S = 2048, D = 1024, H = 16, F = 4096, T = B * S;
  const int D3 = 3 * D;

  char* ws = (char*)d_ws;
  size_t off = 0;
  auto alloc = [&](size_t bytes) {
    void* p = ws + off;
    off += (bytes + 255) & ~(size_t)255;
    return p;
  };
  short* xb   = (short*)alloc((size_t)T * D * 2);     // ln1(x) / ln2(x)
  short* qkv  = (short*)alloc((size_t)T * D3 * 2);    // fused QKV out [T,3D]
  short* ob   = (short*)alloc((size_t)T * D * 2);     // attn out
  short* h2b  = (short*)alloc((size_t)T * D * 2);     // post-attn residual (bf16)
  short* vtg  = (short*)alloc((size_t)T * D * 2);     // V^T [B*H*64, S]
  short* wqkvb  = (short*)alloc((size_t)D3 * D * 2);
  short* wob    = (short*)alloc((size_t)D * D * 2);
  short* wfcb   = (short*)alloc((size_t)F * D * 2);
  short* wprojb = (short*)alloc((size_t)D * F * 2);
  float* bqkv   = (float*)alloc((size_t)D3 * 4);
  short* ub  = qkv;           // u [T,F] aliases qkv(48MB)+ob(16MB), dead by FC

  ProArgs pa;
  const int nqq = D * D / 4;
  pa.s[0] = wq;    pa.d[0] = wqkvb;
  pa.s[1] = wk;    pa.d[1] = wqkvb + (size_t)D * D;
  pa.s[2] = wv;    pa.d[2] = wqkvb + (size_t)2 * D * D;
  pa.s[3] = wo;    pa.d[3] = wob;
  pa.s[4] = wfc;   pa.d[4] = wfcb;
  pa.s[5] = wproj; pa.d[5] = wprojb;
  pa.off[0] = 0;
  pa.off[1] = nqq;
  pa.off[2] = 2 * nqq;
  pa.off[3] = 3 * nqq;
  pa.off[4] = 4 * nqq;
  pa.off[5] = 4 * nqq + F * D / 4;
  pa.off[6] = 4 * nqq + 2 * (F * D / 4);
  pa.ncvt = pa.off[6] / 256;
  pa.bq = bq; pa.bk = bk; pa.bv = bv; pa.bqkv = bqkv;
  pa.h = h; pa.g = ln1_g; pa.b = ln1_b; pa.y = xb;
  prologue<<<dim3(pa.ncvt + 1 + T), 256, 0, stream>>>(pa);

  // attention sub-block (V transposed by QKV epilogue)
  gemm_bt7<1, 0, 0, 1, 1, 0><<<dim3((T / 128) * (D3 / 128)), 256, 0, stream>>>(
      xb, wqkvb, bqkv, nullptr, qkv, T, D3, D, vtg, S, H);
  attn_fwd2<<<dim3((S / 128) * (B * H / 64) * 64), 256, 0, stream>>>(
      qkv, qkv + D, vtg, ob, S, D3, D, H);
  // Wo: out bf16 h2b = acc + bo + h (fp32 res)
  gemm_bt7<1, 1, 0, 0, 0, 0><<<dim3((T / 128) * (D / 128)), 256, 0, stream>>>(
      ob, wob, bo, h, h2b, T, D, D, nullptr, 0, 0);

  // MLP sub-block
  ln_fwd_bf16<<<dim3(T), 256, 0, stream>>>(h2b, ln2_g, ln2_b, xb);
  gemm_bt7<1, 0, 1, 0, 0, 0><<<dim3((T / 128) * (F / 128)), 256, 0, stream>>>(
      xb, wfcb, bfc, nullptr, ub, T, F, D, nullptr, 0, 0);
  // Proj: out fp32 d_out = acc + bproj + h2b (bf16 res)
  gemm_bt7<0, 1, 0, 0, 0, 1><<<dim3((T / 128) * (D / 128)), 256, 0, stream>>>(
      ub, wprojb, bproj, h2b, (float*)d_out, T, D, F, nullptr, 0, 0);
}